// Round 1
// baseline (2819.306 us; speedup 1.0000x reference)
//
#include <hip/hip_runtime.h>
#include <hip/hip_bf16.h>

#define B_ 64
#define S_ 64
#define T_ 64
#define V_ 20000
#define E_ 100
#define U_ 300
#define G4 1200   // 4*U
#define KP 320    // K padded to multiple of 32 for MFMA

typedef __attribute__((ext_vector_type(8))) short short8v;
typedef __attribute__((ext_vector_type(4))) float f32x4;

__device__ __forceinline__ float sigmoidf_(float x) { return 1.0f / (1.0f + expf(-x)); }

// ---------------- init: zero h/c state + seqA (ws is poisoned 0xAA every call) ----
__global__ void zero2_kernel(unsigned* __restrict__ a, int na,
                             unsigned* __restrict__ b, int nb) {
  int stride = gridDim.x * blockDim.x;
  for (int i = blockIdx.x * blockDim.x + threadIdx.x; i < na; i += stride) a[i] = 0u;
  for (int i = blockIdx.x * blockDim.x + threadIdx.x; i < nb; i += stride) b[i] = 0u;
}

// ---------------- dense_w [300][20000] f32 -> transposed bf16 [20000][320], k-pad 0
__global__ __launch_bounds__(256) void cvt_wt_kernel(const float* __restrict__ w,
                                                     __hip_bfloat16* __restrict__ o) {
  __shared__ float tile[32][33];
  int n0 = blockIdx.x * 32, k0 = blockIdx.y * 32;
  int tx = threadIdx.x, ty = threadIdx.y;  // blockDim (32,8)
#pragma unroll
  for (int i = 0; i < 4; ++i) {
    int k = k0 + ty + i * 8;
    float v = 0.f;
    if (k < U_ && n0 + tx < V_) v = w[(size_t)k * V_ + n0 + tx];
    tile[ty + i * 8][tx] = v;
  }
  __syncthreads();
#pragma unroll
  for (int i = 0; i < 4; ++i) {
    int n = n0 + ty + i * 8;
    if (n < V_) o[(size_t)n * KP + k0 + tx] = __float2bfloat16(tile[tx][ty + i * 8]);
  }
}

// ---------------- encoder input pre-GEMM: xpre[s][b][j] = emb[tok[b][s]] @ K + bias
__global__ __launch_bounds__(256) void enc_pre_kernel(const int* __restrict__ tok,
    const float* __restrict__ emb, const float* __restrict__ K,
    const float* __restrict__ bias, float* __restrict__ out) {
  __shared__ float As[32][E_];
  int r0 = blockIdx.y * 32, j0 = blockIdx.x * 128;
  int tid = threadIdx.x;
  for (int i = tid; i < 32 * E_; i += 256) {
    int rl = i / E_, e = i - rl * E_;
    int r = r0 + rl, s = r >> 6, b = r & 63;
    As[rl][e] = emb[(size_t)tok[b * S_ + s] * E_ + e];
  }
  __syncthreads();
  int j = j0 + (tid & 127), rb = tid >> 7;
  if (j >= G4) return;
  float acc[16];
  float bj = bias[j];
#pragma unroll
  for (int i = 0; i < 16; ++i) acc[i] = bj;
  for (int e = 0; e < E_; ++e) {
    float kv = K[e * G4 + j];
#pragma unroll
    for (int i = 0; i < 16; ++i) acc[i] = fmaf(As[rb + i * 2][e], kv, acc[i]);
  }
#pragma unroll
  for (int i = 0; i < 16; ++i) out[(size_t)(r0 + rb + i * 2) * G4 + j] = acc[i];
}

// ---------------- decoder input pre-GEMM: xpre[t][b][j] = dec_in[b][t] @ K + bias
__global__ __launch_bounds__(256) void dec_pre_kernel(const float* __restrict__ din,
    const float* __restrict__ K, const float* __restrict__ bias,
    float* __restrict__ out) {
  __shared__ float As[32][E_];
  int r0 = blockIdx.y * 32, j0 = blockIdx.x * 128;
  int tid = threadIdx.x;
  for (int i = tid; i < 32 * E_; i += 256) {
    int rl = i / E_, e = i - rl * E_;
    int r = r0 + rl, t = r >> 6, b = r & 63;
    As[rl][e] = din[((size_t)b * T_ + t) * E_ + e];
  }
  __syncthreads();
  int j = j0 + (tid & 127), rb = tid >> 7;
  if (j >= G4) return;
  float acc[16];
  float bj = bias[j];
#pragma unroll
  for (int i = 0; i < 16; ++i) acc[i] = bj;
  for (int e = 0; e < E_; ++e) {
    float kv = K[e * G4 + j];
#pragma unroll
    for (int i = 0; i < 16; ++i) acc[i] = fmaf(As[rb + i * 2][e], kv, acc[i]);
  }
#pragma unroll
  for (int i = 0; i < 16; ++i) out[(size_t)(r0 + rb + i * 2) * G4 + j] = acc[i];
}

// ---------------- one LSTM step: z = xpre_t + h @ R; gates; h/c update --------
// grid (19 unit-chunks, 4 batch-groups), block 256 = 16 units x 16 batch rows
__global__ __launch_bounds__(256) void lstm_step_kernel(
    const float* __restrict__ xz, const float* __restrict__ hin,
    const float* __restrict__ cin, const float* __restrict__ R,
    float* __restrict__ hout, float* __restrict__ cout,
    __hip_bfloat16* __restrict__ seqA, int t) {
  __shared__ float hs[16][U_];
  int u0 = blockIdx.x * 16, b0 = blockIdx.y * 16;
  int tid = threadIdx.x;
  for (int i = tid; i < 16 * U_; i += 256) {
    int rl = i / U_, d = i - rl * U_;
    hs[rl][d] = hin[(size_t)(b0 + rl) * U_ + d];
  }
  __syncthreads();
  int tu = tid & 15, tb = tid >> 4;
  int u = u0 + tu;
  int uc = u < U_ ? u : U_ - 1;   // clamp tail chunk; results discarded
  int b = b0 + tb;
  const float* xr = xz + (size_t)b * G4 + uc;
  float a0 = xr[0], a1 = xr[U_], a2 = xr[2 * U_], a3 = xr[3 * U_];
  const float* Rp = R + uc;
#pragma unroll 5
  for (int d = 0; d < U_; ++d) {
    float hv = hs[tb][d];
    a0 = fmaf(hv, Rp[0], a0);
    a1 = fmaf(hv, Rp[U_], a1);
    a2 = fmaf(hv, Rp[2 * U_], a2);
    a3 = fmaf(hv, Rp[3 * U_], a3);
    Rp += G4;
  }
  if (u < U_) {
    float ig = sigmoidf_(a0), fg = sigmoidf_(a1);
    float gg = tanhf(a2), og = sigmoidf_(a3);
    float cn = fmaf(fg, cin[(size_t)b * U_ + u], ig * gg);
    float hn = og * tanhf(cn);
    cout[(size_t)b * U_ + u] = cn;
    hout[(size_t)b * U_ + u] = hn;
    if (seqA) seqA[((size_t)b * T_ + t) * KP + u] = __float2bfloat16(hn);
  }
}

// ---------------- dense: [4096][320]bf16 @ [320][20000]bf16 (B pre-transposed
// [20000][320]) -> logits f32 into d_out, + bias. 128x128 tile, 4 waves 2x2.
__global__ __launch_bounds__(256) void dense_mfma_kernel(
    const __hip_bfloat16* __restrict__ A, const __hip_bfloat16* __restrict__ Bt,
    const float* __restrict__ bias, float* __restrict__ out) {
  __shared__ __align__(16) __hip_bfloat16 Asm[128][40];  // +8 pad: 2-way banks only
  __shared__ __align__(16) __hip_bfloat16 Bsm[128][40];  // [col][k] layout
  int col0 = blockIdx.x * 128, row0 = blockIdx.y * 128;
  int tid = threadIdx.x;
  int lane = tid & 63, wid = tid >> 6;
  int wm = wid >> 1, wn = wid & 1;
  int g16 = lane >> 4, l16 = lane & 15;
  f32x4 acc[4][4];
#pragma unroll
  for (int m = 0; m < 4; ++m)
#pragma unroll
    for (int n = 0; n < 4; ++n) acc[m][n] = (f32x4){0.f, 0.f, 0.f, 0.f};

  for (int kt = 0; kt < KP; kt += 32) {
#pragma unroll
    for (int i = 0; i < 2; ++i) {           // A stage: 128x32 bf16
      int e = (tid + i * 256) * 8;
      int r = e >> 5, kk = e & 31;
      short8v g = *(const short8v*)(A + (size_t)(row0 + r) * KP + kt + kk);
      *(short8v*)(&Asm[r][kk]) = g;
    }
#pragma unroll
    for (int i = 0; i < 2; ++i) {           // B stage: 128 cols x 32 k
      int e = (tid + i * 256) * 8;
      int c = e >> 5, kk = e & 31;
      short8v g = {0, 0, 0, 0, 0, 0, 0, 0};
      if (col0 + c < V_) g = *(const short8v*)(Bt + (size_t)(col0 + c) * KP + kt + kk);
      *(short8v*)(&Bsm[c][kk]) = g;
    }
    __syncthreads();
    short8v af[4], bf[4];
#pragma unroll
    for (int m = 0; m < 4; ++m)
      af[m] = *(const short8v*)(&Asm[wm * 64 + m * 16 + l16][g16 * 8]);
#pragma unroll
    for (int n = 0; n < 4; ++n)
      bf[n] = *(const short8v*)(&Bsm[wn * 64 + n * 16 + l16][g16 * 8]);
#pragma unroll
    for (int m = 0; m < 4; ++m)
#pragma unroll
      for (int n = 0; n < 4; ++n)
        acc[m][n] = __builtin_amdgcn_mfma_f32_16x16x32_bf16(af[m], bf[n], acc[m][n], 0, 0, 0);
    __syncthreads();
  }
  // epilogue: C/D layout col=lane&15, row=4*(lane>>4)+reg  [m89-verified]
#pragma unroll
  for (int m = 0; m < 4; ++m) {
    int rr = row0 + wm * 64 + m * 16 + g16 * 4;
#pragma unroll
    for (int n = 0; n < 4; ++n) {
      int cc = col0 + wn * 64 + n * 16 + l16;
      if (cc < V_) {
        float bv = bias[cc];
#pragma unroll
        for (int r = 0; r < 4; ++r)
          out[(size_t)(rr + r) * V_ + cc] = acc[m][n][r] + bv;
      }
    }
  }
}

// ---------------- softmax over V, in place on d_out; one block per (b,t) row --
__global__ __launch_bounds__(256) void softmax_kernel(float* __restrict__ out) {
  __shared__ float4 rowv[V_ / 4];
  __shared__ float redm[4], reds[4];
  size_t base = (size_t)blockIdx.x * V_;
  float4* gp = (float4*)(out + base);
  int tid = threadIdx.x;
  float lmax = -3.4e38f;
  for (int i = tid; i < V_ / 4; i += 256) {
    float4 v = gp[i];
    rowv[i] = v;
    lmax = fmaxf(lmax, fmaxf(fmaxf(v.x, v.y), fmaxf(v.z, v.w)));
  }
#pragma unroll
  for (int o = 32; o > 0; o >>= 1) lmax = fmaxf(lmax, __shfl_down(lmax, o));
  if ((tid & 63) == 0) redm[tid >> 6] = lmax;
  __syncthreads();
  float rmax = fmaxf(fmaxf(redm[0], redm[1]), fmaxf(redm[2], redm[3]));
  float lsum = 0.f;
  for (int i = tid; i < V_ / 4; i += 256) {
    float4 v = rowv[i];
    v.x = expf(v.x - rmax); v.y = expf(v.y - rmax);
    v.z = expf(v.z - rmax); v.w = expf(v.w - rmax);
    rowv[i] = v;
    lsum += v.x + v.y + v.z + v.w;
  }
#pragma unroll
  for (int o = 32; o > 0; o >>= 1) lsum += __shfl_down(lsum, o);
  if ((tid & 63) == 0) reds[tid >> 6] = lsum;
  __syncthreads();
  float inv = 1.0f / (reds[0] + reds[1] + reds[2] + reds[3]);
  for (int i = tid; i < V_ / 4; i += 256) {
    float4 v = rowv[i];
    v.x *= inv; v.y *= inv; v.z *= inv; v.w *= inv;
    gp[i] = v;
  }
}

extern "C" void kernel_launch(void* const* d_in, const int* in_sizes, int n_in,
                              void* d_out, int out_size, void* d_ws, size_t ws_size,
                              hipStream_t stream) {
  const int*   tok    = (const int*)d_in[0];
  const float* dec_in = (const float*)d_in[1];
  const float* emb    = (const float*)d_in[2];
  const float* encK   = (const float*)d_in[3];
  const float* encR   = (const float*)d_in[4];
  const float* encB   = (const float*)d_in[5];
  const float* decK   = (const float*)d_in[6];
  const float* decR   = (const float*)d_in[7];
  const float* decB   = (const float*)d_in[8];
  const float* dW     = (const float*)d_in[9];
  const float* dB     = (const float*)d_in[10];
  float* out = (float*)d_out;
  (void)in_sizes; (void)n_in; (void)out_size; (void)ws_size;

  char* ws = (char*)d_ws;
  size_t off = 0;
  auto alloc = [&](size_t bytes) {
    void* p = ws + off;
    off += (bytes + 255) & ~(size_t)255;
    return p;
  };
  float* xpre = (float*)alloc((size_t)S_ * B_ * G4 * 4);           // 19.7 MB (enc, reused dec)
  float* hc   = (float*)alloc((size_t)4 * B_ * U_ * 4);            // h[2], c[2]
  __hip_bfloat16* seqA = (__hip_bfloat16*)alloc((size_t)B_ * T_ * KP * 2);  // 2.6 MB
  __hip_bfloat16* wBt  = (__hip_bfloat16*)alloc((size_t)V_ * KP * 2);       // 12.8 MB
  float* hA[2] = { hc, hc + B_ * U_ };
  float* cA[2] = { hc + 2 * B_ * U_, hc + 3 * B_ * U_ };

  // ws is re-poisoned to 0xAA each call: zero h/c and seqA (incl. k-pad)
  zero2_kernel<<<512, 256, 0, stream>>>((unsigned*)hc, 4 * B_ * U_,
                                        (unsigned*)seqA, B_ * T_ * KP / 2);
  cvt_wt_kernel<<<dim3(V_ / 32, KP / 32), dim3(32, 8), 0, stream>>>(dW, wBt);

  enc_pre_kernel<<<dim3(10, 128), 256, 0, stream>>>(tok, emb, encK, encB, xpre);
  for (int t = 0; t < S_; ++t)
    lstm_step_kernel<<<dim3(19, 4), 256, 0, stream>>>(
        xpre + (size_t)t * B_ * G4, hA[t & 1], cA[t & 1], encR,
        hA[(t + 1) & 1], cA[(t + 1) & 1], (__hip_bfloat16*)nullptr, t);

  dec_pre_kernel<<<dim3(10, 128), 256, 0, stream>>>(dec_in, decK, decB, xpre);
  for (int t = 0; t < T_; ++t)
    lstm_step_kernel<<<dim3(19, 4), 256, 0, stream>>>(
        xpre + (size_t)t * B_ * G4, hA[t & 1], cA[t & 1], decR,
        hA[(t + 1) & 1], cA[(t + 1) & 1], seqA, t);

  dense_mfma_kernel<<<dim3((V_ + 127) / 128, 32), 256, 0, stream>>>(seqA, wBt, dB, out);
  softmax_kernel<<<B_ * T_, 256, 0, stream>>>(out);
}

// Round 2
// 1985.082 us; speedup vs baseline: 1.4202x; 1.4202x over previous
//
#include <hip/hip_runtime.h>
#include <hip/hip_bf16.h>

#define B_ 64
#define S_ 64
#define T_ 64
#define V_ 20000
#define E_ 100
#define U_ 300
#define G4 1200   // 4*U
#define KP 320    // dense K padded to multiple of 32 for MFMA

typedef __attribute__((ext_vector_type(8))) short short8v;
typedef __attribute__((ext_vector_type(4))) float f32x4;

__device__ __forceinline__ float sigmoidf_(float x) { return 1.0f / (1.0f + expf(-x)); }

__device__ __forceinline__ unsigned f2bf_bits(float x) {
  __hip_bfloat16 h = __float2bfloat16(x);
  unsigned short u;
  __builtin_memcpy(&u, &h, 2);
  return (unsigned)u;
}

// ---- R [300][1200] f32 -> packed bf16x2 [300][600] (col 2c low, 2c+1 high) ----
__global__ __launch_bounds__(256) void cvt_r_kernel(const float* __restrict__ Re,
    const float* __restrict__ Rd, unsigned* __restrict__ oe,
    unsigned* __restrict__ od) {
  int i = blockIdx.x * 256 + threadIdx.x;
  if (i >= U_ * 600) return;
  int d = i / 600, c = i - d * 600;
  size_t s = (size_t)d * G4 + 2 * c;
  oe[i] = f2bf_bits(Re[s]) | (f2bf_bits(Re[s + 1]) << 16);
  od[i] = f2bf_bits(Rd[s]) | (f2bf_bits(Rd[s + 1]) << 16);
}

// ---- dense_w [300][20000] f32 -> transposed bf16 [20000][320], k-pad zeroed ----
__global__ __launch_bounds__(256) void cvt_wt_kernel(const float* __restrict__ w,
                                                     __hip_bfloat16* __restrict__ o) {
  __shared__ float tile[32][33];
  int n0 = blockIdx.x * 32, k0 = blockIdx.y * 32;
  int tx = threadIdx.x, ty = threadIdx.y;  // blockDim (32,8)
#pragma unroll
  for (int i = 0; i < 4; ++i) {
    int k = k0 + ty + i * 8;
    float v = 0.f;
    if (k < U_ && n0 + tx < V_) v = w[(size_t)k * V_ + n0 + tx];
    tile[ty + i * 8][tx] = v;
  }
  __syncthreads();
#pragma unroll
  for (int i = 0; i < 4; ++i) {
    int n = n0 + ty + i * 8;
    if (n < V_) o[(size_t)n * KP + k0 + tx] = __float2bfloat16(tile[tx][ty + i * 8]);
  }
}

// ---- encoder input pre-GEMM: xpre[s][b][j] = emb[tok[b][s]] @ K + bias --------
__global__ __launch_bounds__(256) void enc_pre_kernel(const int* __restrict__ tok,
    const float* __restrict__ emb, const float* __restrict__ K,
    const float* __restrict__ bias, float* __restrict__ out) {
  __shared__ float As[32][E_];
  int r0 = blockIdx.y * 32, j0 = blockIdx.x * 128;
  int tid = threadIdx.x;
  for (int i = tid; i < 32 * E_; i += 256) {
    int rl = i / E_, e = i - rl * E_;
    int r = r0 + rl, s = r >> 6, b = r & 63;
    As[rl][e] = emb[(size_t)tok[b * S_ + s] * E_ + e];
  }
  __syncthreads();
  int j = j0 + (tid & 127), rb = tid >> 7;
  if (j >= G4) return;
  float acc[16];
  float bj = bias[j];
#pragma unroll
  for (int i = 0; i < 16; ++i) acc[i] = bj;
  for (int e = 0; e < E_; ++e) {
    float kv = K[e * G4 + j];
#pragma unroll
    for (int i = 0; i < 16; ++i) acc[i] = fmaf(As[rb + i * 2][e], kv, acc[i]);
  }
#pragma unroll
  for (int i = 0; i < 16; ++i) out[(size_t)(r0 + rb + i * 2) * G4 + j] = acc[i];
}

// ---- decoder input pre-GEMM: xpre[t][b][j] = dec_in[b][t] @ K + bias ----------
__global__ __launch_bounds__(256) void dec_pre_kernel(const float* __restrict__ din,
    const float* __restrict__ K, const float* __restrict__ bias,
    float* __restrict__ out) {
  __shared__ float As[32][E_];
  int r0 = blockIdx.y * 32, j0 = blockIdx.x * 128;
  int tid = threadIdx.x;
  for (int i = tid; i < 32 * E_; i += 256) {
    int rl = i / E_, e = i - rl * E_;
    int r = r0 + rl, t = r >> 6, b = r & 63;
    As[rl][e] = din[((size_t)b * T_ + t) * E_ + e];
  }
  __syncthreads();
  int j = j0 + (tid & 127), rb = tid >> 7;
  if (j >= G4) return;
  float acc[16];
  float bj = bias[j];
#pragma unroll
  for (int i = 0; i < 16; ++i) acc[i] = bj;
  for (int e = 0; e < E_; ++e) {
    float kv = K[e * G4 + j];
#pragma unroll
    for (int i = 0; i < 16; ++i) acc[i] = fmaf(As[rb + i * 2][e], kv, acc[i]);
  }
#pragma unroll
  for (int i = 0; i < 16; ++i) out[(size_t)(r0 + rb + i * 2) * G4 + j] = acc[i];
}

// ---- fused 2-LSTM recurrence: 1 block per batch row, both phases, 128 steps ---
// block 640 threads: threads 0..599 each own packed col pair (2t, 2t+1) of z;
// threads 0..299 do the gate update. h/c persist in LDS across all steps.
__global__ __launch_bounds__(640) void lstm_fused_kernel(
    const float* __restrict__ xpreE, const float* __restrict__ xpreD,
    const unsigned* __restrict__ Re, const unsigned* __restrict__ Rd,
    __hip_bfloat16* __restrict__ seqA) {
  __shared__ __align__(16) float h_lds[U_];
  __shared__ float c_lds[U_];
  __shared__ float z_lds[G4];
  int b = blockIdx.x;
  int tid = threadIdx.x;
  if (tid < U_) { h_lds[tid] = 0.f; c_lds[tid] = 0.f; }
  __syncthreads();
  for (int phase = 0; phase < 2; ++phase) {
    const float* xp = phase ? xpreD : xpreE;
    const unsigned* R = phase ? Rd : Re;
    for (int t = 0; t < 64; ++t) {
      if (tid < 600) {
        const float* xr = xp + ((size_t)t * B_ + b) * G4;
        int j0 = tid * 2;
        float a0 = xr[j0], a1 = xr[j0 + 1];
        const unsigned* Rp = R + tid;
        const float4* h4 = (const float4*)h_lds;
#pragma unroll 3
        for (int dq = 0; dq < U_ / 4; ++dq) {
          float4 hv = h4[dq];
          unsigned p0 = Rp[0], p1 = Rp[600], p2 = Rp[1200], p3 = Rp[1800];
          a0 = fmaf(hv.x, __uint_as_float(p0 << 16), a0);
          a1 = fmaf(hv.x, __uint_as_float(p0 & 0xffff0000u), a1);
          a0 = fmaf(hv.y, __uint_as_float(p1 << 16), a0);
          a1 = fmaf(hv.y, __uint_as_float(p1 & 0xffff0000u), a1);
          a0 = fmaf(hv.z, __uint_as_float(p2 << 16), a0);
          a1 = fmaf(hv.z, __uint_as_float(p2 & 0xffff0000u), a1);
          a0 = fmaf(hv.w, __uint_as_float(p3 << 16), a0);
          a1 = fmaf(hv.w, __uint_as_float(p3 & 0xffff0000u), a1);
          Rp += 2400;
        }
        z_lds[j0] = a0;
        z_lds[j0 + 1] = a1;
      }
      __syncthreads();   // z complete; everyone done reading h
      if (tid < U_) {
        float ig = sigmoidf_(z_lds[tid]);
        float fg = sigmoidf_(z_lds[tid + U_]);
        float gg = tanhf(z_lds[tid + 2 * U_]);
        float og = sigmoidf_(z_lds[tid + 3 * U_]);
        float cn = fmaf(fg, c_lds[tid], ig * gg);
        float hn = og * tanhf(cn);
        c_lds[tid] = cn;
        h_lds[tid] = hn;
        if (phase)
          seqA[((size_t)b * T_ + t) * KP + tid] = __float2bfloat16(hn);
      }
      __syncthreads();   // h/c updated before next step reads them
    }
  }
}

// ---- dense: [4096][320]bf16 @ Bt[20000][320]bf16 -> logits f32 + bias ---------
__global__ __launch_bounds__(256) void dense_mfma_kernel(
    const __hip_bfloat16* __restrict__ A, const __hip_bfloat16* __restrict__ Bt,
    const float* __restrict__ bias, float* __restrict__ out) {
  __shared__ __align__(16) __hip_bfloat16 Asm[128][40];
  __shared__ __align__(16) __hip_bfloat16 Bsm[128][40];
  int col0 = blockIdx.x * 128, row0 = blockIdx.y * 128;
  int tid = threadIdx.x;
  int lane = tid & 63, wid = tid >> 6;
  int wm = wid >> 1, wn = wid & 1;
  int g16 = lane >> 4, l16 = lane & 15;
  f32x4 acc[4][4];
#pragma unroll
  for (int m = 0; m < 4; ++m)
#pragma unroll
    for (int n = 0; n < 4; ++n) acc[m][n] = (f32x4){0.f, 0.f, 0.f, 0.f};

  for (int kt = 0; kt < KP; kt += 32) {
#pragma unroll
    for (int i = 0; i < 2; ++i) {
      int e = (tid + i * 256) * 8;
      int r = e >> 5, kk = e & 31;
      short8v g = *(const short8v*)(A + (size_t)(row0 + r) * KP + kt + kk);
      *(short8v*)(&Asm[r][kk]) = g;
    }
#pragma unroll
    for (int i = 0; i < 2; ++i) {
      int e = (tid + i * 256) * 8;
      int c = e >> 5, kk = e & 31;
      short8v g = {0, 0, 0, 0, 0, 0, 0, 0};
      if (col0 + c < V_) g = *(const short8v*)(Bt + (size_t)(col0 + c) * KP + kt + kk);
      *(short8v*)(&Bsm[c][kk]) = g;
    }
    __syncthreads();
    short8v af[4], bf[4];
#pragma unroll
    for (int m = 0; m < 4; ++m)
      af[m] = *(const short8v*)(&Asm[wm * 64 + m * 16 + l16][g16 * 8]);
#pragma unroll
    for (int n = 0; n < 4; ++n)
      bf[n] = *(const short8v*)(&Bsm[wn * 64 + n * 16 + l16][g16 * 8]);
#pragma unroll
    for (int m = 0; m < 4; ++m)
#pragma unroll
      for (int n = 0; n < 4; ++n)
        acc[m][n] = __builtin_amdgcn_mfma_f32_16x16x32_bf16(af[m], bf[n], acc[m][n], 0, 0, 0);
    __syncthreads();
  }
#pragma unroll
  for (int m = 0; m < 4; ++m) {
    int rr = row0 + wm * 64 + m * 16 + g16 * 4;
#pragma unroll
    for (int n = 0; n < 4; ++n) {
      int cc = col0 + wn * 64 + n * 16 + l16;
      if (cc < V_) {
        float bv = bias[cc];
#pragma unroll
        for (int r = 0; r < 4; ++r)
          out[(size_t)(rr + r) * V_ + cc] = acc[m][n][r] + bv;
      }
    }
  }
}

// ---- softmax over V, in place on d_out; one block per (b,t) row ---------------
__global__ __launch_bounds__(256) void softmax_kernel(float* __restrict__ out) {
  __shared__ float4 rowv[V_ / 4];
  __shared__ float redm[4], reds[4];
  size_t base = (size_t)blockIdx.x * V_;
  float4* gp = (float4*)(out + base);
  int tid = threadIdx.x;
  float lmax = -3.4e38f;
  for (int i = tid; i < V_ / 4; i += 256) {
    float4 v = gp[i];
    rowv[i] = v;
    lmax = fmaxf(lmax, fmaxf(fmaxf(v.x, v.y), fmaxf(v.z, v.w)));
  }
#pragma unroll
  for (int o = 32; o > 0; o >>= 1) lmax = fmaxf(lmax, __shfl_down(lmax, o));
  if ((tid & 63) == 0) redm[tid >> 6] = lmax;
  __syncthreads();
  float rmax = fmaxf(fmaxf(redm[0], redm[1]), fmaxf(redm[2], redm[3]));
  float lsum = 0.f;
  for (int i = tid; i < V_ / 4; i += 256) {
    float4 v = rowv[i];
    v.x = expf(v.x - rmax); v.y = expf(v.y - rmax);
    v.z = expf(v.z - rmax); v.w = expf(v.w - rmax);
    rowv[i] = v;
    lsum += v.x + v.y + v.z + v.w;
  }
#pragma unroll
  for (int o = 32; o > 0; o >>= 1) lsum += __shfl_down(lsum, o);
  if ((tid & 63) == 0) reds[tid >> 6] = lsum;
  __syncthreads();
  float inv = 1.0f / (reds[0] + reds[1] + reds[2] + reds[3]);
  for (int i = tid; i < V_ / 4; i += 256) {
    float4 v = rowv[i];
    v.x *= inv; v.y *= inv; v.z *= inv; v.w *= inv;
    gp[i] = v;
  }
}

extern "C" void kernel_launch(void* const* d_in, const int* in_sizes, int n_in,
                              void* d_out, int out_size, void* d_ws, size_t ws_size,
                              hipStream_t stream) {
  const int*   tok    = (const int*)d_in[0];
  const float* dec_in = (const float*)d_in[1];
  const float* emb    = (const float*)d_in[2];
  const float* encK   = (const float*)d_in[3];
  const float* encR   = (const float*)d_in[4];
  const float* encB   = (const float*)d_in[5];
  const float* decK   = (const float*)d_in[6];
  const float* decR   = (const float*)d_in[7];
  const float* decB   = (const float*)d_in[8];
  const float* dW     = (const float*)d_in[9];
  const float* dB     = (const float*)d_in[10];
  float* out = (float*)d_out;
  (void)in_sizes; (void)n_in; (void)out_size; (void)ws_size;

  char* ws = (char*)d_ws;
  size_t off = 0;
  auto alloc = [&](size_t bytes) {
    void* p = ws + off;
    off += (bytes + 255) & ~(size_t)255;
    return p;
  };
  float* xpreE = (float*)alloc((size_t)S_ * B_ * G4 * 4);                  // 19.7 MB
  float* xpreD = (float*)alloc((size_t)T_ * B_ * G4 * 4);                  // 19.7 MB
  __hip_bfloat16* seqA = (__hip_bfloat16*)alloc((size_t)B_ * T_ * KP * 2); // 2.6 MB
  __hip_bfloat16* wBt  = (__hip_bfloat16*)alloc((size_t)V_ * KP * 2);      // 12.8 MB
  unsigned* RePk = (unsigned*)alloc((size_t)U_ * 600 * 4);                 // 0.72 MB
  unsigned* RdPk = (unsigned*)alloc((size_t)U_ * 600 * 4);                 // 0.72 MB

  // seqA pad cols (300..319) stay 0xAA: harmless — they multiply wBt's zeroed
  // k-pad in the dense GEMM (finite bf16 * 0 = 0), so no zero-init needed.
  cvt_r_kernel<<<(U_ * 600 + 255) / 256, 256, 0, stream>>>(encR, decR, RePk, RdPk);
  cvt_wt_kernel<<<dim3(V_ / 32, KP / 32), dim3(32, 8), 0, stream>>>(dW, wBt);
  enc_pre_kernel<<<dim3(10, 128), 256, 0, stream>>>(tok, emb, encK, encB, xpreE);
  dec_pre_kernel<<<dim3(10, 128), 256, 0, stream>>>(dec_in, decK, decB, xpreD);

  lstm_fused_kernel<<<B_, 640, 0, stream>>>(xpreE, xpreD, RePk, RdPk, seqA);

  dense_mfma_kernel<<<dim3((V_ + 127) / 128, 32), 256, 0, stream>>>(seqA, wBt, dB, out);
  softmax_kernel<<<B_ * T_, 256, 0, stream>>>(out);
}